// Round 17
// baseline (155.984 us; speedup 1.0000x reference)
//
#include <hip/hip_runtime.h>

#define IN_C 17
#define HID  64
#define OUTC 32

#define CH   8192      // edges per pass-A block
#define TA   512       // pass-A threads
#define NBP  512       // padded bucket count (bucket = dst>>8; N<=131072)
#define BCAP 5632      // pass-B stage capacity
#define MAXG 2048      // persistent gather grid (8 blocks/CU x 256 CU)

typedef __attribute__((ext_vector_type(2))) float f2;
typedef __attribute__((ext_vector_type(8))) short bf16x8;
typedef __attribute__((ext_vector_type(4))) float f32x4;
__device__ __forceinline__ f2 mkf2(float x, float y) { f2 r; r.x = x; r.y = y; return r; }

__device__ __forceinline__ unsigned short f2bf(float f) {
    unsigned u = __float_as_uint(f);
    u += 0x7fffu + ((u >> 16) & 1u);      // round-nearest-even
    return (unsigned short)(u >> 16);
}
__device__ __forceinline__ float bflo(unsigned u) { return __uint_as_float(u << 16); }
__device__ __forceinline__ float bfhi(unsigned u) { return __uint_as_float(u & 0xffff0000u); }

// ===== pass A: bin edges by dst>>8 + pool zero + (block 0) W2 fragment pack =====
__global__ __launch_bounds__(TA) void k_binA(const int* __restrict__ src,
        const int* __restrict__ dst, int E,
        int* __restrict__ outbuf, int* __restrict__ cntmat, int* __restrict__ offmat,
        const float* __restrict__ W2, uint4* __restrict__ w2frag,
        float* __restrict__ pool, int poolN) {
    __shared__ int cnt[NBP];
    __shared__ int off[NBP];
    __shared__ int stage[CH];
    int t = threadIdx.x;
    // zero pool+cntg (replaces pathological hipMemsetAsync fill)
    for (int i = (int)(blockIdx.x * TA + t); i < poolN; i += (int)(gridDim.x * TA))
        pool[i] = 0.f;
    // pack W2 into MFMA B-fragment layout (block 0): frag f = kt*2+nt; lane l holds
    // B[k = kt*32 + (l>>4)*8 + j][c = nt*16 + (l&15)], j=0..7
    if (blockIdx.x == 0 && t < 256) {
        int f = t >> 6, l = t & 63;
        int kt = f >> 1, nt = f & 1;
        int kbase = kt * 32 + (l >> 4) * 8;
        int c = nt * 16 + (l & 15);
        unsigned short v[8];
#pragma unroll
        for (int j = 0; j < 8; ++j) v[j] = f2bf(W2[(kbase + j) * OUTC + c]);
        uint4 o;
        o.x = (unsigned)v[0] | ((unsigned)v[1] << 16);
        o.y = (unsigned)v[2] | ((unsigned)v[3] << 16);
        o.z = (unsigned)v[4] | ((unsigned)v[5] << 16);
        o.w = (unsigned)v[6] | ((unsigned)v[7] << 16);
        w2frag[f * 64 + l] = o;
    }
    long base = (long)blockIdx.x * CH;
    int nE = (int)(E - base); if (nE > CH) nE = CH;
    cnt[t] = 0;
    __syncthreads();
    int bk[16], pk[16], rk[16];
#pragma unroll
    for (int j = 0; j < 16; ++j) {
        int idx = t + j * TA;
        if (idx < nE) {
            long e = base + idx;
            int d = __builtin_nontemporal_load(&dst[e]);
            int s = __builtin_nontemporal_load(&src[e]);
            int b = d >> 8;
            bk[j] = b;
            pk[j] = s | ((d & 255) << 17);
            rk[j] = atomicAdd(&cnt[b], 1);
        } else bk[j] = -1;
    }
    __syncthreads();
    int c = cnt[t];
    off[t] = c;
    __syncthreads();
    int inc = c;
    for (int s = 1; s < NBP; s <<= 1) {
        int add = (t >= s) ? off[t - s] : 0;
        __syncthreads();
        inc += add; off[t] = inc;
        __syncthreads();
    }
    int excl = inc - c;
    __syncthreads();
    off[t] = excl;
    __syncthreads();
#pragma unroll
    for (int j = 0; j < 16; ++j)
        if (bk[j] >= 0) stage[off[bk[j]] + rk[j]] = pk[j];
    __syncthreads();
    for (int i = t; i < nE; i += TA) outbuf[base + i] = stage[i];
    cntmat[blockIdx.x * NBP + t] = c;
    offmat[blockIdx.x * NBP + t] = excl;
}

// === pass B: per bucket, gather runs, self-computed base, emit CSR + meta + bf16 xs ===
__global__ __launch_bounds__(TA) void k_binB(const int* __restrict__ outbuf,
        const int* __restrict__ cntmat, const int* __restrict__ offmat,
        int nblkA, int N,
        int* __restrict__ csr, int2* __restrict__ meta,
        const float* __restrict__ x, unsigned* __restrict__ xs16h,
        unsigned short* __restrict__ xs17h) {
    __shared__ int segc[256], sego[256], segs[256];
    __shared__ int ndeg[256], noff[256];
    __shared__ int red[TA];
    __shared__ int stage[BCAP];
    int t = threadIdx.x, b = blockIdx.x;
    // column-sum for buckets < b (reduced later into this block's global base)
    int colsum = 0;
    if (t < b) {
        for (int i = 0; i < nblkA; ++i) colsum += cntmat[i * NBP + t];
    }
    if (t < 256) {
        int cc = 0, ss = 0;
        if (t < nblkA) { cc = cntmat[t * NBP + b]; ss = offmat[t * NBP + b]; }
        segc[t] = cc; segs[t] = ss; sego[t] = cc;
        ndeg[t] = 0;
    }
    __syncthreads();
    {
        int c = (t < 256) ? sego[t] : 0;
        int inc = c;
        for (int s = 1; s < 256; s <<= 1) {
            int add = (t < 256 && t >= s) ? sego[t - s] : 0;
            __syncthreads();
            if (t < 256) { inc += add; sego[t] = inc; }
            __syncthreads();
        }
        if (t < 256) sego[t] = inc - c;
    }
    __syncthreads();
    int wave = t >> 6, lane = t & 63;
    for (int i = wave; i < nblkA; i += TA / 64) {
        int c = segc[i], so = sego[i];
        long gs = (long)i * CH + segs[i];
        for (int l = lane; l < c; l += 64) {
            int p = so + l;
            if (p < BCAP) stage[p] = __builtin_nontemporal_load(&outbuf[gs + l]);
        }
    }
    __syncthreads();
    int T = sego[255] + segc[255];
    if (T > BCAP) T = BCAP;
    int mypk[11], myrk[11], ne = 0;
    for (int k = t; k < T; k += TA) {
        int p = stage[k];
        int l = (p >> 17) & 255;
        myrk[ne] = atomicAdd(&ndeg[l], 1);
        mypk[ne] = p;
        ne++;
    }
    __syncthreads();
    {
        int c = (t < 256) ? ndeg[t] : 0;
        if (t < 256) noff[t] = c;
        __syncthreads();
        int inc = c;
        for (int s = 1; s < 256; s <<= 1) {
            int add = (t < 256 && t >= s) ? noff[t - s] : 0;
            __syncthreads();
            if (t < 256) { inc += add; noff[t] = inc; }
            __syncthreads();
        }
        if (t < 256) noff[t] = inc - c;
    }
    __syncthreads();
    // reduce colsum -> global bucket base
    red[t] = colsum;
    __syncthreads();
    for (int s = TA / 2; s > 0; s >>= 1) {
        if (t < s) red[t] += red[t + s];
        __syncthreads();
    }
    int gb = red[0];
    int n0 = b << 8;
    if (t < 256 && n0 + t < N) {
        int n = n0 + t;
        meta[n] = make_int2(gb + noff[t], ndeg[t]);
        float dinv = rsqrtf((float)(ndeg[t] + 1));
        const float* xr = x + (size_t)n * IN_C;
        unsigned* xo = xs16h + (size_t)n * 8;
#pragma unroll
        for (int w2 = 0; w2 < 8; ++w2) {
            unsigned lo = f2bf(xr[2 * w2] * dinv);
            unsigned hi = f2bf(xr[2 * w2 + 1] * dinv);
            xo[w2] = lo | (hi << 16);
        }
        xs17h[n] = f2bf(xr[16] * dinv);
    }
    for (int j = 0; j < ne; ++j) {
        int p = mypk[j];
        int l = (p >> 17) & 255;
        csr[gb + noff[l] + myrk[j]] = p & 0x1FFFF;
    }
}

// ---------- layer 1 (persistent): gather -> fold -> matvec1 -> in-block MFMA mm2 -> fp8 hs2 ----------
__global__ __launch_bounds__(256) void k_gather1(
        const uint4* __restrict__ xs16v, const unsigned short* __restrict__ xs17h,
        const int* __restrict__ csr, const int2* __restrict__ meta,
        const float* __restrict__ W1, const float* __restrict__ b1,
        const uint4* __restrict__ w2frag, unsigned char* __restrict__ hs2b,
        int N, int ntiles) {
    __shared__ __align__(16) float aggx[16][20];
    __shared__ float dinv_sh[16];
    __shared__ __align__(16) float h1sh[16][68];   // holds dinv*relu(h1), f32

    int tid = threadIdx.x;
    int ch = tid & 63;
    float w1r[IN_C];
#pragma unroll
    for (int k = 0; k < IN_C; ++k) w1r[k] = W1[k * HID + ch];
    float b1v = b1[ch];
    int wv = tid >> 6, l = tid & 63;
    // B fragments loaded once per block (only waves 0-1 consume)
    bf16x8 bA = *(const bf16x8*)&w2frag[(0 + (wv & 1)) * 64 + l];
    bf16x8 bB = *(const bf16x8*)&w2frag[(2 + (wv & 1)) * 64 + l];
    int ln = tid >> 4, sl = tid & 15;
    int s0 = tid >> 6;

    for (int tile = blockIdx.x; tile < ntiles; tile += gridDim.x) {
        int n0 = tile * 16;
        int n = n0 + ln;
        f2 acc[8];
#pragma unroll
        for (int j = 0; j < 8; ++j) acc[j] = mkf2(0.f, 0.f);
        float a17 = 0.f;
        if (n < N) {
            int2 m = meta[n];
            int start = m.x, cnt = m.y, end = start + cnt;
            auto body = [&](int s) {
                uint4 v0 = xs16v[(size_t)s * 2];
                uint4 v1 = xs16v[(size_t)s * 2 + 1];
                acc[0] += mkf2(bflo(v0.x), bfhi(v0.x));
                acc[1] += mkf2(bflo(v0.y), bfhi(v0.y));
                acc[2] += mkf2(bflo(v0.z), bfhi(v0.z));
                acc[3] += mkf2(bflo(v0.w), bfhi(v0.w));
                acc[4] += mkf2(bflo(v1.x), bfhi(v1.x));
                acc[5] += mkf2(bflo(v1.y), bfhi(v1.y));
                acc[6] += mkf2(bflo(v1.z), bfhi(v1.z));
                acc[7] += mkf2(bflo(v1.w), bfhi(v1.w));
                a17 += bflo((unsigned)xs17h[s]);
            };
            for (int k = start + sl; k < end; k += 16)
                body(__builtin_nontemporal_load(&csr[k]));
            if (sl == 0) {                                   // self loop
                body(n);
                dinv_sh[ln] = rsqrtf((float)(cnt + 1));
            }
        }
        float a[16];
#pragma unroll
        for (int j = 0; j < 8; ++j) { a[2 * j] = acc[j].x; a[2 * j + 1] = acc[j].y; }
#pragma unroll
        for (int j = 0; j < 8; ++j) {
            float tt = (sl & 8) ? a[j + 8] : a[j];
            float uu = (sl & 8) ? a[j] : a[j + 8];
            a[j] = tt + __shfl_xor(uu, 8);
        }
#pragma unroll
        for (int j = 0; j < 4; ++j) {
            float tt = (sl & 4) ? a[j + 4] : a[j];
            float uu = (sl & 4) ? a[j] : a[j + 4];
            a[j] = tt + __shfl_xor(uu, 4);
        }
#pragma unroll
        for (int j = 0; j < 2; ++j) {
            float tt = (sl & 2) ? a[j + 2] : a[j];
            float uu = (sl & 2) ? a[j] : a[j + 2];
            a[j] = tt + __shfl_xor(uu, 2);
        }
        {
            float tt = (sl & 1) ? a[1] : a[0];
            float uu = (sl & 1) ? a[0] : a[1];
            a[0] = tt + __shfl_xor(uu, 1);
        }
        a17 += __shfl_xor(a17, 1);
        a17 += __shfl_xor(a17, 2);
        a17 += __shfl_xor(a17, 4);
        a17 += __shfl_xor(a17, 8);
        aggx[ln][sl] = a[0];
        if (sl == 0) aggx[ln][16] = a17;
        __syncthreads();
        // matvec1 + bias + relu; h1sh = dinv * relu(...)  (f32)
#pragma unroll
        for (int rep = 0; rep < 4; ++rep) {
            int slot = s0 + rep * 4;
            int nn = n0 + slot;
            if (nn < N) {
                const float4* ap = (const float4*)aggx[slot];
                float4 A0 = ap[0], A1 = ap[1], A2 = ap[2], A3 = ap[3];
                float a16 = aggx[slot][16];
                float dot = A0.x * w1r[0]  + A0.y * w1r[1]  + A0.z * w1r[2]  + A0.w * w1r[3]
                          + A1.x * w1r[4]  + A1.y * w1r[5]  + A1.z * w1r[6]  + A1.w * w1r[7]
                          + A2.x * w1r[8]  + A2.y * w1r[9]  + A2.z * w1r[10] + A2.w * w1r[11]
                          + A3.x * w1r[12] + A3.y * w1r[13] + A3.z * w1r[14] + A3.w * w1r[15]
                          + a16  * w1r[16];
                float dv = dinv_sh[slot];
                h1sh[slot][ch] = dv * fmaxf(dv * dot + b1v, 0.f);
            }
        }
        __syncthreads();
        // mm2 via MFMA: wave wv (<2) computes N-tile wv (cols wv*16..+15)
        if (wv < 2) {
            int row = l & 15, kq = l >> 4;
            const float4* hp = (const float4*)&h1sh[row][kq * 8];
            float4 f0v = hp[0], f1v = hp[1];
            const float4* hq = (const float4*)&h1sh[row][32 + kq * 8];
            float4 g0v = hq[0], g1v = hq[1];
            bf16x8 a0, a1;
            a0[0] = (short)f2bf(f0v.x); a0[1] = (short)f2bf(f0v.y);
            a0[2] = (short)f2bf(f0v.z); a0[3] = (short)f2bf(f0v.w);
            a0[4] = (short)f2bf(f1v.x); a0[5] = (short)f2bf(f1v.y);
            a0[6] = (short)f2bf(f1v.z); a0[7] = (short)f2bf(f1v.w);
            a1[0] = (short)f2bf(g0v.x); a1[1] = (short)f2bf(g0v.y);
            a1[2] = (short)f2bf(g0v.z); a1[3] = (short)f2bf(g0v.w);
            a1[4] = (short)f2bf(g1v.x); a1[5] = (short)f2bf(g1v.y);
            a1[6] = (short)f2bf(g1v.z); a1[7] = (short)f2bf(g1v.w);
            f32x4 d = {0.f, 0.f, 0.f, 0.f};
            d = __builtin_amdgcn_mfma_f32_16x16x32_bf16(a0, bA, d, 0, 0, 0);
            d = __builtin_amdgcn_mfma_f32_16x16x32_bf16(a1, bB, d, 0, 0, 0);
            int rbase = (l >> 4) * 4;
#pragma unroll
            for (int r = 0; r < 4; ++r) {
                int node = n0 + rbase + r;
                if (node < N) {
                    unsigned pk = (unsigned)__builtin_amdgcn_cvt_pk_fp8_f32(d[r], 0.f, 0, false);
                    hs2b[(size_t)node * 32 + wv * 16 + (l & 15)] = (unsigned char)(pk & 0xFFu);
                }
            }
        }
        __syncthreads();   // protect h1sh/aggx for next tile
    }
}

// ---------- layer 2 gather (persistent): 1 lane/edge, fp8 rows (HW cvt) + pool ----------
__global__ __launch_bounds__(256) void k_gather2(
        const uint4* __restrict__ hs2v, const int* __restrict__ csr,
        const int2* __restrict__ meta, const float* __restrict__ b2,
        const int* __restrict__ batch, float* pool, float* cntg,
        int N, int ntiles) {
    __shared__ __align__(16) float cont[16][OUTC];
    __shared__ int bsh[16];
    int tid = threadIdx.x;
    int ln = tid >> 4, sl = tid & 15;

    for (int tile = blockIdx.x; tile < ntiles; tile += gridDim.x) {
        int n0 = tile * 16;
        int n = n0 + ln;
        f2 acc[16];
#pragma unroll
        for (int j = 0; j < 16; ++j) acc[j] = mkf2(0.f, 0.f);
        float dinv = 0.f;
        if (n < N) {
            int2 m = meta[n];
            int start = m.x, cnt = m.y, end = start + cnt;
            dinv = rsqrtf((float)(cnt + 1));
            auto body = [&](int s) {
                const uint4* rp = hs2v + (size_t)s * 2;
                uint4 v0 = rp[0], v1 = rp[1];
                f2 t;
                t = __builtin_amdgcn_cvt_pk_f32_fp8((int)v0.x, false); acc[0]  += t;
                t = __builtin_amdgcn_cvt_pk_f32_fp8((int)v0.x, true);  acc[1]  += t;
                t = __builtin_amdgcn_cvt_pk_f32_fp8((int)v0.y, false); acc[2]  += t;
                t = __builtin_amdgcn_cvt_pk_f32_fp8((int)v0.y, true);  acc[3]  += t;
                t = __builtin_amdgcn_cvt_pk_f32_fp8((int)v0.z, false); acc[4]  += t;
                t = __builtin_amdgcn_cvt_pk_f32_fp8((int)v0.z, true);  acc[5]  += t;
                t = __builtin_amdgcn_cvt_pk_f32_fp8((int)v0.w, false); acc[6]  += t;
                t = __builtin_amdgcn_cvt_pk_f32_fp8((int)v0.w, true);  acc[7]  += t;
                t = __builtin_amdgcn_cvt_pk_f32_fp8((int)v1.x, false); acc[8]  += t;
                t = __builtin_amdgcn_cvt_pk_f32_fp8((int)v1.x, true);  acc[9]  += t;
                t = __builtin_amdgcn_cvt_pk_f32_fp8((int)v1.y, false); acc[10] += t;
                t = __builtin_amdgcn_cvt_pk_f32_fp8((int)v1.y, true);  acc[11] += t;
                t = __builtin_amdgcn_cvt_pk_f32_fp8((int)v1.z, false); acc[12] += t;
                t = __builtin_amdgcn_cvt_pk_f32_fp8((int)v1.z, true);  acc[13] += t;
                t = __builtin_amdgcn_cvt_pk_f32_fp8((int)v1.w, false); acc[14] += t;
                t = __builtin_amdgcn_cvt_pk_f32_fp8((int)v1.w, true);  acc[15] += t;
            };
            for (int k = start + sl; k < end; k += 16)
                body(__builtin_nontemporal_load(&csr[k]));
            if (sl == 0) body(n);                            // self loop
        }
        float a[32];
#pragma unroll
        for (int j = 0; j < 16; ++j) { a[2 * j] = acc[j].x; a[2 * j + 1] = acc[j].y; }
        // halving fold: lane sl ends with channels (2sl, 2sl+1) in a[0], a[1]
#pragma unroll
        for (int j = 0; j < 16; ++j) {
            float tt = (sl & 8) ? a[j + 16] : a[j];
            float uu = (sl & 8) ? a[j] : a[j + 16];
            a[j] = tt + __shfl_xor(uu, 8);
        }
#pragma unroll
        for (int j = 0; j < 8; ++j) {
            float tt = (sl & 4) ? a[j + 8] : a[j];
            float uu = (sl & 4) ? a[j] : a[j + 8];
            a[j] = tt + __shfl_xor(uu, 4);
        }
#pragma unroll
        for (int j = 0; j < 4; ++j) {
            float tt = (sl & 2) ? a[j + 4] : a[j];
            float uu = (sl & 2) ? a[j] : a[j + 4];
            a[j] = tt + __shfl_xor(uu, 2);
        }
#pragma unroll
        for (int j = 0; j < 2; ++j) {
            float tt = (sl & 1) ? a[j + 2] : a[j];
            float uu = (sl & 1) ? a[j] : a[j + 2];
            a[j] = tt + __shfl_xor(uu, 1);
        }
        if (n < N) {
            float c0 = dinv * a[0] + b2[2 * sl];
            float c1 = dinv * a[1] + b2[2 * sl + 1];
            *(float2*)&cont[ln][2 * sl] = make_float2(c0, c1);
            if (sl == 0) bsh[ln] = batch[n];
        } else {
            *(float2*)&cont[ln][2 * sl] = make_float2(0.f, 0.f);
            if (sl == 0) bsh[ln] = -1;
        }
        __syncthreads();
        if (tid < OUTC) {
            int c = tid;
            float run = 0.f; int cur = -1;
            for (int j = 0; j < 16; ++j) {
                int bj = bsh[j];
                if (bj < 0) continue;
                if (bj == cur) run += cont[j][c];
                else {
                    if (cur >= 0) atomicAdd(&pool[(size_t)cur * OUTC + c], run);
                    cur = bj; run = cont[j][c];
                }
            }
            if (cur >= 0) atomicAdd(&pool[(size_t)cur * OUTC + c], run);
            if (c == 0) {
                float crun = 0.f; cur = -1;
                for (int j = 0; j < 16; ++j) {
                    int bj = bsh[j];
                    if (bj < 0) continue;
                    if (bj == cur) crun += 1.f;
                    else {
                        if (cur >= 0) atomicAdd(&cntg[cur], crun);
                        cur = bj; crun = 1.f;
                    }
                }
                if (cur >= 0) atomicAdd(&cntg[cur], crun);
            }
        }
        __syncthreads();   // protect cont/bsh for next tile
    }
}

// ---------- final: pooled mean -> fc1(relu) -> fc2 ----------
__global__ void k_final(const float* __restrict__ pool, const float* __restrict__ cntg,
                        const float* __restrict__ Wf1, const float* __restrict__ bf1,
                        const float* __restrict__ Wf2, const float* __restrict__ bf2,
                        float* out, int G) {
    __shared__ float p[OUTC], t[OUTC];
    int g = blockIdx.x;
    int c = threadIdx.x;
    float csafe = fmaxf(cntg[g], 1.0f);
    p[c] = pool[g * OUTC + c] / csafe;
    __syncthreads();
    float acc = bf1[c];
#pragma unroll
    for (int k = 0; k < OUTC; ++k) acc += p[k] * Wf1[k * OUTC + c];
    t[c] = fmaxf(acc, 0.f);
    __syncthreads();
    float acc2 = bf2[c];
#pragma unroll
    for (int k = 0; k < OUTC; ++k) acc2 += t[k] * Wf2[k * OUTC + c];
    out[g * OUTC + c] = acc2;
}

extern "C" void kernel_launch(void* const* d_in, const int* in_sizes, int n_in,
                              void* d_out, int out_size, void* d_ws, size_t ws_size,
                              hipStream_t stream) {
    const float* x    = (const float*)d_in[0];
    const int*   ei   = (const int*)  d_in[1];
    const int*   batch= (const int*)  d_in[2];
    const float* W1   = (const float*)d_in[3];
    const float* b1   = (const float*)d_in[4];
    const float* W2   = (const float*)d_in[5];
    const float* b2   = (const float*)d_in[6];
    const float* Wf1  = (const float*)d_in[7];
    const float* bf1  = (const float*)d_in[8];
    const float* Wf2  = (const float*)d_in[9];
    const float* bf2  = (const float*)d_in[10];

    const int N = in_sizes[0] / IN_C;
    const int E = in_sizes[1] / 2;
    const int G = out_size / OUTC;
    const int* src = ei;
    const int* dst = ei + E;

    const int nblkA = (E + CH - 1) / CH;
    const int NB    = (N + 255) >> 8;

    // ---- workspace layout ----
    char* w = (char*)d_ws;
    int*   csr      = (int*)w;   w += (size_t)E * sizeof(int);
    int2*  meta     = (int2*)w;  w += (size_t)N * sizeof(int2);
    unsigned* xs16h = (unsigned*)w; w += (size_t)N * 8 * sizeof(unsigned);
    unsigned char* hs2 = (unsigned char*)w; w += (size_t)N * 32;   // fp8 rows, 32B
    unsigned short* xs17h = (unsigned short*)w; w += (size_t)N * sizeof(unsigned short);
    w = (char*)(((size_t)w + 15) & ~(size_t)15);
    float* pool     = (float*)w; w += (size_t)G * OUTC * sizeof(float);
    float* cntg     = (float*)w; w += (size_t)G * sizeof(float);
    w = (char*)(((size_t)w + 15) & ~(size_t)15);
    int*   outbuf   = (int*)w;   w += (size_t)E * sizeof(int);
    int*   cntmat   = (int*)w;   w += (size_t)nblkA * NBP * sizeof(int);
    int*   offmat   = (int*)w;   w += (size_t)nblkA * NBP * sizeof(int);
    w = (char*)(((size_t)w + 15) & ~(size_t)15);
    uint4* w2frag   = (uint4*)w; w += 4 * 64 * sizeof(uint4);

    const int poolN = G * OUTC + G;   // pool + cntg are contiguous floats
    const int ntiles = (N + 15) / 16;
    const int gg = ntiles < MAXG ? ntiles : MAXG;

    // CSR build (counting sort) + fused x prep + W2 fragment pack + pool zero
    k_binA<<<nblkA, TA, 0, stream>>>(src, dst, E, outbuf, cntmat, offmat,
                                     W2, w2frag, pool, poolN);
    k_binB<<<NB, TA, 0, stream>>>(outbuf, cntmat, offmat, nblkA, N,
                                  csr, meta, x, xs16h, xs17h);

    // layer 1 (persistent): gather + matvec1 + in-block MFMA mm2 -> fp8 hs2
    dim3 blk(256);
    k_gather1<<<gg, blk, 0, stream>>>((const uint4*)xs16h, xs17h, csr, meta,
                                      W1, b1, w2frag, hs2, N, ntiles);

    // layer 2 gather + pool (persistent, fp8 rows L2-resident)
    k_gather2<<<gg, blk, 0, stream>>>((const uint4*)hs2, csr, meta,
                                      b2, batch, pool, cntg, N, ntiles);

    // readout
    k_final<<<G, OUTC, 0, stream>>>(pool, cntg, Wf1, bf1, Wf2, bf2, (float*)d_out, G);
}

// Round 18
// 140.101 us; speedup vs baseline: 1.1134x; 1.1134x over previous
//
#include <hip/hip_runtime.h>

#define IN_C 17
#define HID  64
#define OUTC 32

#define CH   8192      // edges per pass-A block
#define TA   512       // pass-A threads
#define NBP  512       // padded bucket count (bucket = dst>>8; N<=131072)
#define BCAP 5632      // pass-B stage capacity
#define BS_BLKS 8
#define MAXG 2048      // persistent gather grid (8 blocks/CU x 256 CU)

typedef __attribute__((ext_vector_type(2))) float f2;
typedef __attribute__((ext_vector_type(8))) short bf16x8;
typedef __attribute__((ext_vector_type(4))) float f32x4;
__device__ __forceinline__ f2 mkf2(float x, float y) { f2 r; r.x = x; r.y = y; return r; }

__device__ __forceinline__ unsigned short f2bf(float f) {
    unsigned u = __float_as_uint(f);
    u += 0x7fffu + ((u >> 16) & 1u);      // round-nearest-even
    return (unsigned short)(u >> 16);
}
__device__ __forceinline__ float bflo(unsigned u) { return __uint_as_float(u << 16); }
__device__ __forceinline__ float bfhi(unsigned u) { return __uint_as_float(u & 0xffff0000u); }

// ===== pass A: bin edges by dst>>8 + pool zero + (block 0) W2 fragment pack =====
__global__ __launch_bounds__(TA) void k_binA(const int* __restrict__ src,
        const int* __restrict__ dst, int E,
        int* __restrict__ outbuf, int* __restrict__ cntmat, int* __restrict__ offmat,
        const float* __restrict__ W2, uint4* __restrict__ w2frag,
        float* __restrict__ pool, int poolN) {
    __shared__ int cnt[NBP];
    __shared__ int off[NBP];
    __shared__ int stage[CH];
    int t = threadIdx.x;
    // zero pool+cntg (replaces pathological hipMemsetAsync fill)
    for (int i = (int)(blockIdx.x * TA + t); i < poolN; i += (int)(gridDim.x * TA))
        pool[i] = 0.f;
    // pack W2 into MFMA B-fragment layout (block 0): frag f = kt*2+nt; lane l holds
    // B[k = kt*32 + (l>>4)*8 + j][c = nt*16 + (l&15)], j=0..7
    if (blockIdx.x == 0 && t < 256) {
        int f = t >> 6, l = t & 63;
        int kt = f >> 1, nt = f & 1;
        int kbase = kt * 32 + (l >> 4) * 8;
        int c = nt * 16 + (l & 15);
        unsigned short v[8];
#pragma unroll
        for (int j = 0; j < 8; ++j) v[j] = f2bf(W2[(kbase + j) * OUTC + c]);
        uint4 o;
        o.x = (unsigned)v[0] | ((unsigned)v[1] << 16);
        o.y = (unsigned)v[2] | ((unsigned)v[3] << 16);
        o.z = (unsigned)v[4] | ((unsigned)v[5] << 16);
        o.w = (unsigned)v[6] | ((unsigned)v[7] << 16);
        w2frag[f * 64 + l] = o;
    }
    long base = (long)blockIdx.x * CH;
    int nE = (int)(E - base); if (nE > CH) nE = CH;
    cnt[t] = 0;
    __syncthreads();
    int bk[16], pk[16], rk[16];
#pragma unroll
    for (int j = 0; j < 16; ++j) {
        int idx = t + j * TA;
        if (idx < nE) {
            long e = base + idx;
            int d = __builtin_nontemporal_load(&dst[e]);
            int s = __builtin_nontemporal_load(&src[e]);
            int b = d >> 8;
            bk[j] = b;
            pk[j] = s | ((d & 255) << 17);
            rk[j] = atomicAdd(&cnt[b], 1);
        } else bk[j] = -1;
    }
    __syncthreads();
    int c = cnt[t];
    off[t] = c;
    __syncthreads();
    int inc = c;
    for (int s = 1; s < NBP; s <<= 1) {
        int add = (t >= s) ? off[t - s] : 0;
        __syncthreads();
        inc += add; off[t] = inc;
        __syncthreads();
    }
    int excl = inc - c;
    __syncthreads();
    off[t] = excl;
    __syncthreads();
#pragma unroll
    for (int j = 0; j < 16; ++j)
        if (bk[j] >= 0) stage[off[bk[j]] + rk[j]] = pk[j];
    __syncthreads();
    for (int i = t; i < nE; i += TA) outbuf[base + i] = stage[i];
    cntmat[blockIdx.x * NBP + t] = c;
    offmat[blockIdx.x * NBP + t] = excl;
}

// ============ bucket totals (parallel partial) + exclusive scan ============
__global__ __launch_bounds__(NBP) void k_bsum1(const int* __restrict__ cntmat,
        int nblkA, int* __restrict__ part) {
    int t = threadIdx.x, b = blockIdx.x;
    int per = (nblkA + BS_BLKS - 1) / BS_BLKS;
    int i0 = b * per, i1 = min(i0 + per, nblkA);
    int s = 0;
    for (int i = i0; i < i1; ++i) s += cntmat[i * NBP + t];
    part[b * NBP + t] = s;
}

__global__ __launch_bounds__(NBP) void k_bsum2(const int* __restrict__ part,
        int* __restrict__ bbase) {
    __shared__ int sh[NBP];
    int t = threadIdx.x;
    int s = 0;
#pragma unroll
    for (int i = 0; i < BS_BLKS; ++i) s += part[i * NBP + t];
    sh[t] = s;
    __syncthreads();
    int inc = s;
    for (int st = 1; st < NBP; st <<= 1) {
        int add = (t >= st) ? sh[t - st] : 0;
        __syncthreads();
        inc += add; sh[t] = inc;
        __syncthreads();
    }
    bbase[t] = inc - s;
}

// === pass B: per bucket, gather runs, emit CSR + meta(start,deg) + bf16 xs (fused prep) ===
__global__ __launch_bounds__(TA) void k_binB(const int* __restrict__ outbuf,
        const int* __restrict__ cntmat, const int* __restrict__ offmat,
        const int* __restrict__ bbase, int nblkA, int N,
        int* __restrict__ csr, int2* __restrict__ meta,
        const float* __restrict__ x, unsigned* __restrict__ xs16h,
        unsigned short* __restrict__ xs17h) {
    __shared__ int segc[256], sego[256], segs[256];
    __shared__ int ndeg[256], noff[256];
    __shared__ int stage[BCAP];
    int t = threadIdx.x, b = blockIdx.x;
    if (t < 256) {
        int cc = 0, ss = 0;
        if (t < nblkA) { cc = cntmat[t * NBP + b]; ss = offmat[t * NBP + b]; }
        segc[t] = cc; segs[t] = ss; sego[t] = cc;
        ndeg[t] = 0;
    }
    __syncthreads();
    {
        int c = (t < 256) ? sego[t] : 0;
        int inc = c;
        for (int s = 1; s < 256; s <<= 1) {
            int add = (t < 256 && t >= s) ? sego[t - s] : 0;
            __syncthreads();
            if (t < 256) { inc += add; sego[t] = inc; }
            __syncthreads();
        }
        if (t < 256) sego[t] = inc - c;
    }
    __syncthreads();
    int wave = t >> 6, lane = t & 63;
    for (int i = wave; i < nblkA; i += TA / 64) {
        int c = segc[i], so = sego[i];
        long gs = (long)i * CH + segs[i];
        for (int l = lane; l < c; l += 64) {
            int p = so + l;
            if (p < BCAP) stage[p] = __builtin_nontemporal_load(&outbuf[gs + l]);
        }
    }
    __syncthreads();
    int T = sego[255] + segc[255];
    if (T > BCAP) T = BCAP;
    int mypk[11], myrk[11], ne = 0;
    for (int k = t; k < T; k += TA) {
        int p = stage[k];
        int l = (p >> 17) & 255;
        myrk[ne] = atomicAdd(&ndeg[l], 1);
        mypk[ne] = p;
        ne++;
    }
    __syncthreads();
    {
        int c = (t < 256) ? ndeg[t] : 0;
        if (t < 256) noff[t] = c;
        __syncthreads();
        int inc = c;
        for (int s = 1; s < 256; s <<= 1) {
            int add = (t < 256 && t >= s) ? noff[t - s] : 0;
            __syncthreads();
            if (t < 256) { inc += add; noff[t] = inc; }
            __syncthreads();
        }
        if (t < 256) noff[t] = inc - c;
    }
    __syncthreads();
    int gb = bbase[b];
    int n0 = b << 8;
    if (t < 256 && n0 + t < N) {
        int n = n0 + t;
        meta[n] = make_int2(gb + noff[t], ndeg[t]);
        float dinv = rsqrtf((float)(ndeg[t] + 1));
        const float* xr = x + (size_t)n * IN_C;
        unsigned* xo = xs16h + (size_t)n * 8;
#pragma unroll
        for (int w2 = 0; w2 < 8; ++w2) {
            unsigned lo = f2bf(xr[2 * w2] * dinv);
            unsigned hi = f2bf(xr[2 * w2 + 1] * dinv);
            xo[w2] = lo | (hi << 16);
        }
        xs17h[n] = f2bf(xr[16] * dinv);
    }
    for (int j = 0; j < ne; ++j) {
        int p = mypk[j];
        int l = (p >> 17) & 255;
        csr[gb + noff[l] + myrk[j]] = p & 0x1FFFF;
    }
}

// ---------- layer 1 (persistent): gather -> fold -> matvec1 -> in-block MFMA mm2 -> fp8 hs2 ----------
__global__ __launch_bounds__(256) void k_gather1(
        const uint4* __restrict__ xs16v, const unsigned short* __restrict__ xs17h,
        const int* __restrict__ csr, const int2* __restrict__ meta,
        const float* __restrict__ W1, const float* __restrict__ b1,
        const uint4* __restrict__ w2frag, unsigned char* __restrict__ hs2b,
        int N, int ntiles) {
    __shared__ __align__(16) float aggx[16][20];
    __shared__ float dinv_sh[16];
    __shared__ __align__(16) float h1sh[16][68];   // holds dinv*relu(h1), f32

    int tid = threadIdx.x;
    int ch = tid & 63;
    float w1r[IN_C];
#pragma unroll
    for (int k = 0; k < IN_C; ++k) w1r[k] = W1[k * HID + ch];
    float b1v = b1[ch];
    int wv = tid >> 6, l = tid & 63;
    // B fragments loaded once per block (only waves 0-1 consume)
    bf16x8 bA = *(const bf16x8*)&w2frag[(0 + (wv & 1)) * 64 + l];
    bf16x8 bB = *(const bf16x8*)&w2frag[(2 + (wv & 1)) * 64 + l];
    int ln = tid >> 4, sl = tid & 15;
    int s0 = tid >> 6;

    for (int tile = blockIdx.x; tile < ntiles; tile += gridDim.x) {
        int n0 = tile * 16;
        int n = n0 + ln;
        f2 acc[8];
#pragma unroll
        for (int j = 0; j < 8; ++j) acc[j] = mkf2(0.f, 0.f);
        float a17 = 0.f;
        if (n < N) {
            int2 m = meta[n];
            int start = m.x, cnt = m.y, end = start + cnt;
            auto body = [&](int s) {
                uint4 v0 = xs16v[(size_t)s * 2];
                uint4 v1 = xs16v[(size_t)s * 2 + 1];
                acc[0] += mkf2(bflo(v0.x), bfhi(v0.x));
                acc[1] += mkf2(bflo(v0.y), bfhi(v0.y));
                acc[2] += mkf2(bflo(v0.z), bfhi(v0.z));
                acc[3] += mkf2(bflo(v0.w), bfhi(v0.w));
                acc[4] += mkf2(bflo(v1.x), bfhi(v1.x));
                acc[5] += mkf2(bflo(v1.y), bfhi(v1.y));
                acc[6] += mkf2(bflo(v1.z), bfhi(v1.z));
                acc[7] += mkf2(bflo(v1.w), bfhi(v1.w));
                a17 += bflo((unsigned)xs17h[s]);
            };
            for (int k = start + sl; k < end; k += 16)
                body(__builtin_nontemporal_load(&csr[k]));
            if (sl == 0) {                                   // self loop
                body(n);
                dinv_sh[ln] = rsqrtf((float)(cnt + 1));
            }
        }
        float a[16];
#pragma unroll
        for (int j = 0; j < 8; ++j) { a[2 * j] = acc[j].x; a[2 * j + 1] = acc[j].y; }
#pragma unroll
        for (int j = 0; j < 8; ++j) {
            float tt = (sl & 8) ? a[j + 8] : a[j];
            float uu = (sl & 8) ? a[j] : a[j + 8];
            a[j] = tt + __shfl_xor(uu, 8);
        }
#pragma unroll
        for (int j = 0; j < 4; ++j) {
            float tt = (sl & 4) ? a[j + 4] : a[j];
            float uu = (sl & 4) ? a[j] : a[j + 4];
            a[j] = tt + __shfl_xor(uu, 4);
        }
#pragma unroll
        for (int j = 0; j < 2; ++j) {
            float tt = (sl & 2) ? a[j + 2] : a[j];
            float uu = (sl & 2) ? a[j] : a[j + 2];
            a[j] = tt + __shfl_xor(uu, 2);
        }
        {
            float tt = (sl & 1) ? a[1] : a[0];
            float uu = (sl & 1) ? a[0] : a[1];
            a[0] = tt + __shfl_xor(uu, 1);
        }
        a17 += __shfl_xor(a17, 1);
        a17 += __shfl_xor(a17, 2);
        a17 += __shfl_xor(a17, 4);
        a17 += __shfl_xor(a17, 8);
        aggx[ln][sl] = a[0];
        if (sl == 0) aggx[ln][16] = a17;
        __syncthreads();
        // matvec1 + bias + relu; h1sh = dinv * relu(...)  (f32)
#pragma unroll
        for (int rep = 0; rep < 4; ++rep) {
            int slot = s0 + rep * 4;
            int nn = n0 + slot;
            if (nn < N) {
                const float4* ap = (const float4*)aggx[slot];
                float4 A0 = ap[0], A1 = ap[1], A2 = ap[2], A3 = ap[3];
                float a16 = aggx[slot][16];
                float dot = A0.x * w1r[0]  + A0.y * w1r[1]  + A0.z * w1r[2]  + A0.w * w1r[3]
                          + A1.x * w1r[4]  + A1.y * w1r[5]  + A1.z * w1r[6]  + A1.w * w1r[7]
                          + A2.x * w1r[8]  + A2.y * w1r[9]  + A2.z * w1r[10] + A2.w * w1r[11]
                          + A3.x * w1r[12] + A3.y * w1r[13] + A3.z * w1r[14] + A3.w * w1r[15]
                          + a16  * w1r[16];
                float dv = dinv_sh[slot];
                h1sh[slot][ch] = dv * fmaxf(dv * dot + b1v, 0.f);
            }
        }
        __syncthreads();
        // mm2 via MFMA: wave wv (<2) computes N-tile wv (cols wv*16..+15)
        if (wv < 2) {
            int row = l & 15, kq = l >> 4;
            const float4* hp = (const float4*)&h1sh[row][kq * 8];
            float4 f0v = hp[0], f1v = hp[1];
            const float4* hq = (const float4*)&h1sh[row][32 + kq * 8];
            float4 g0v = hq[0], g1v = hq[1];
            bf16x8 a0, a1;
            a0[0] = (short)f2bf(f0v.x); a0[1] = (short)f2bf(f0v.y);
            a0[2] = (short)f2bf(f0v.z); a0[3] = (short)f2bf(f0v.w);
            a0[4] = (short)f2bf(f1v.x); a0[5] = (short)f2bf(f1v.y);
            a0[6] = (short)f2bf(f1v.z); a0[7] = (short)f2bf(f1v.w);
            a1[0] = (short)f2bf(g0v.x); a1[1] = (short)f2bf(g0v.y);
            a1[2] = (short)f2bf(g0v.z); a1[3] = (short)f2bf(g0v.w);
            a1[4] = (short)f2bf(g1v.x); a1[5] = (short)f2bf(g1v.y);
            a1[6] = (short)f2bf(g1v.z); a1[7] = (short)f2bf(g1v.w);
            f32x4 d = {0.f, 0.f, 0.f, 0.f};
            d = __builtin_amdgcn_mfma_f32_16x16x32_bf16(a0, bA, d, 0, 0, 0);
            d = __builtin_amdgcn_mfma_f32_16x16x32_bf16(a1, bB, d, 0, 0, 0);
            int rbase = (l >> 4) * 4;
#pragma unroll
            for (int r = 0; r < 4; ++r) {
                int node = n0 + rbase + r;
                if (node < N) {
                    unsigned pk = (unsigned)__builtin_amdgcn_cvt_pk_fp8_f32(d[r], 0.f, 0, false);
                    hs2b[(size_t)node * 32 + wv * 16 + (l & 15)] = (unsigned char)(pk & 0xFFu);
                }
            }
        }
        __syncthreads();   // protect h1sh/aggx for next tile
    }
}

// ---------- layer 2 gather (persistent): 1 lane/edge, fp8 rows (HW cvt) + pool ----------
__global__ __launch_bounds__(256) void k_gather2(
        const uint4* __restrict__ hs2v, const int* __restrict__ csr,
        const int2* __restrict__ meta, const float* __restrict__ b2,
        const int* __restrict__ batch, float* pool, float* cntg,
        int N, int ntiles) {
    __shared__ __align__(16) float cont[16][OUTC];
    __shared__ int bsh[16];
    int tid = threadIdx.x;
    int ln = tid >> 4, sl = tid & 15;

    for (int tile = blockIdx.x; tile < ntiles; tile += gridDim.x) {
        int n0 = tile * 16;
        int n = n0 + ln;
        f2 acc[16];
#pragma unroll
        for (int j = 0; j < 16; ++j) acc[j] = mkf2(0.f, 0.f);
        float dinv = 0.f;
        if (n < N) {
            int2 m = meta[n];
            int start = m.x, cnt = m.y, end = start + cnt;
            dinv = rsqrtf((float)(cnt + 1));
            auto body = [&](int s) {
                const uint4* rp = hs2v + (size_t)s * 2;
                uint4 v0 = rp[0], v1 = rp[1];
                f2 t;
                t = __builtin_amdgcn_cvt_pk_f32_fp8((int)v0.x, false); acc[0]  += t;
                t = __builtin_amdgcn_cvt_pk_f32_fp8((int)v0.x, true);  acc[1]  += t;
                t = __builtin_amdgcn_cvt_pk_f32_fp8((int)v0.y, false); acc[2]  += t;
                t = __builtin_amdgcn_cvt_pk_f32_fp8((int)v0.y, true);  acc[3]  += t;
                t = __builtin_amdgcn_cvt_pk_f32_fp8((int)v0.z, false); acc[4]  += t;
                t = __builtin_amdgcn_cvt_pk_f32_fp8((int)v0.z, true);  acc[5]  += t;
                t = __builtin_amdgcn_cvt_pk_f32_fp8((int)v0.w, false); acc[6]  += t;
                t = __builtin_amdgcn_cvt_pk_f32_fp8((int)v0.w, true);  acc[7]  += t;
                t = __builtin_amdgcn_cvt_pk_f32_fp8((int)v1.x, false); acc[8]  += t;
                t = __builtin_amdgcn_cvt_pk_f32_fp8((int)v1.x, true);  acc[9]  += t;
                t = __builtin_amdgcn_cvt_pk_f32_fp8((int)v1.y, false); acc[10] += t;
                t = __builtin_amdgcn_cvt_pk_f32_fp8((int)v1.y, true);  acc[11] += t;
                t = __builtin_amdgcn_cvt_pk_f32_fp8((int)v1.z, false); acc[12] += t;
                t = __builtin_amdgcn_cvt_pk_f32_fp8((int)v1.z, true);  acc[13] += t;
                t = __builtin_amdgcn_cvt_pk_f32_fp8((int)v1.w, false); acc[14] += t;
                t = __builtin_amdgcn_cvt_pk_f32_fp8((int)v1.w, true);  acc[15] += t;
            };
            for (int k = start + sl; k < end; k += 16)
                body(__builtin_nontemporal_load(&csr[k]));
            if (sl == 0) body(n);                            // self loop
        }
        float a[32];
#pragma unroll
        for (int j = 0; j < 16; ++j) { a[2 * j] = acc[j].x; a[2 * j + 1] = acc[j].y; }
        // halving fold: lane sl ends with channels (2sl, 2sl+1) in a[0], a[1]
#pragma unroll
        for (int j = 0; j < 16; ++j) {
            float tt = (sl & 8) ? a[j + 16] : a[j];
            float uu = (sl & 8) ? a[j] : a[j + 16];
            a[j] = tt + __shfl_xor(uu, 8);
        }
#pragma unroll
        for (int j = 0; j < 8; ++j) {
            float tt = (sl & 4) ? a[j + 8] : a[j];
            float uu = (sl & 4) ? a[j] : a[j + 8];
            a[j] = tt + __shfl_xor(uu, 4);
        }
#pragma unroll
        for (int j = 0; j < 4; ++j) {
            float tt = (sl & 2) ? a[j + 4] : a[j];
            float uu = (sl & 2) ? a[j] : a[j + 4];
            a[j] = tt + __shfl_xor(uu, 2);
        }
#pragma unroll
        for (int j = 0; j < 2; ++j) {
            float tt = (sl & 1) ? a[j + 2] : a[j];
            float uu = (sl & 1) ? a[j] : a[j + 2];
            a[j] = tt + __shfl_xor(uu, 1);
        }
        if (n < N) {
            float c0 = dinv * a[0] + b2[2 * sl];
            float c1 = dinv * a[1] + b2[2 * sl + 1];
            *(float2*)&cont[ln][2 * sl] = make_float2(c0, c1);
            if (sl == 0) bsh[ln] = batch[n];
        } else {
            *(float2*)&cont[ln][2 * sl] = make_float2(0.f, 0.f);
            if (sl == 0) bsh[ln] = -1;
        }
        __syncthreads();
        if (tid < OUTC) {
            int c = tid;
            float run = 0.f; int cur = -1;
            for (int j = 0; j < 16; ++j) {
                int bj = bsh[j];
                if (bj < 0) continue;
                if (bj == cur) run += cont[j][c];
                else {
                    if (cur >= 0) atomicAdd(&pool[(size_t)cur * OUTC + c], run);
                    cur = bj; run = cont[j][c];
                }
            }
            if (cur >= 0) atomicAdd(&pool[(size_t)cur * OUTC + c], run);
            if (c == 0) {
                float crun = 0.f; cur = -1;
                for (int j = 0; j < 16; ++j) {
                    int bj = bsh[j];
                    if (bj < 0) continue;
                    if (bj == cur) crun += 1.f;
                    else {
                        if (cur >= 0) atomicAdd(&cntg[cur], crun);
                        cur = bj; crun = 1.f;
                    }
                }
                if (cur >= 0) atomicAdd(&cntg[cur], crun);
            }
        }
        __syncthreads();   // protect cont/bsh for next tile
    }
}

// ---------- final: pooled mean -> fc1(relu) -> fc2 ----------
__global__ void k_final(const float* __restrict__ pool, const float* __restrict__ cntg,
                        const float* __restrict__ Wf1, const float* __restrict__ bf1,
                        const float* __restrict__ Wf2, const float* __restrict__ bf2,
                        float* out, int G) {
    __shared__ float p[OUTC], t[OUTC];
    int g = blockIdx.x;
    int c = threadIdx.x;
    float csafe = fmaxf(cntg[g], 1.0f);
    p[c] = pool[g * OUTC + c] / csafe;
    __syncthreads();
    float acc = bf1[c];
#pragma unroll
    for (int k = 0; k < OUTC; ++k) acc += p[k] * Wf1[k * OUTC + c];
    t[c] = fmaxf(acc, 0.f);
    __syncthreads();
    float acc2 = bf2[c];
#pragma unroll
    for (int k = 0; k < OUTC; ++k) acc2 += t[k] * Wf2[k * OUTC + c];
    out[g * OUTC + c] = acc2;
}

extern "C" void kernel_launch(void* const* d_in, const int* in_sizes, int n_in,
                              void* d_out, int out_size, void* d_ws, size_t ws_size,
                              hipStream_t stream) {
    const float* x    = (const float*)d_in[0];
    const int*   ei   = (const int*)  d_in[1];
    const int*   batch= (const int*)  d_in[2];
    const float* W1   = (const float*)d_in[3];
    const float* b1   = (const float*)d_in[4];
    const float* W2   = (const float*)d_in[5];
    const float* b2   = (const float*)d_in[6];
    const float* Wf1  = (const float*)d_in[7];
    const float* bf1  = (const float*)d_in[8];
    const float* Wf2  = (const float*)d_in[9];
    const float* bf2  = (const float*)d_in[10];

    const int N = in_sizes[0] / IN_C;
    const int E = in_sizes[1] / 2;
    const int G = out_size / OUTC;
    const int* src = ei;
    const int* dst = ei + E;

    const int nblkA = (E + CH - 1) / CH;
    const int NB    = (N + 255) >> 8;

    // ---- workspace layout ----
    char* w = (char*)d_ws;
    int*   csr      = (int*)w;   w += (size_t)E * sizeof(int);
    int2*  meta     = (int2*)w;  w += (size_t)N * sizeof(int2);
    unsigned* xs16h = (unsigned*)w; w += (size_t)N * 8 * sizeof(unsigned);
    unsigned char* hs2 = (unsigned char*)w; w += (size_t)N * 32;   // fp8 rows, 32B
    unsigned short* xs17h = (unsigned short*)w; w += (size_t)N * sizeof(unsigned short);
    w = (char*)(((size_t)w + 15) & ~(size_t)15);
    float* pool     = (float*)w; w += (size_t)G * OUTC * sizeof(float);
    float* cntg     = (float*)w; w += (size_t)G * sizeof(float);
    w = (char*)(((size_t)w + 15) & ~(size_t)15);
    int*   outbuf   = (int*)w;   w += (size_t)E * sizeof(int);
    int*   cntmat   = (int*)w;   w += (size_t)nblkA * NBP * sizeof(int);
    int*   offmat   = (int*)w;   w += (size_t)nblkA * NBP * sizeof(int);
    int*   bbase    = (int*)w;   w += NBP * sizeof(int);
    int*   part     = (int*)w;   w += BS_BLKS * NBP * sizeof(int);
    w = (char*)(((size_t)w + 15) & ~(size_t)15);
    uint4* w2frag   = (uint4*)w; w += 4 * 64 * sizeof(uint4);

    const int poolN = G * OUTC + G;   // pool + cntg are contiguous floats
    const int ntiles = (N + 15) / 16;
    const int gg = ntiles < MAXG ? ntiles : MAXG;

    // CSR build (counting sort) + fused x prep + W2 fragment pack + pool zero
    k_binA<<<nblkA, TA, 0, stream>>>(src, dst, E, outbuf, cntmat, offmat,
                                     W2, w2frag, pool, poolN);
    k_bsum1<<<BS_BLKS, NBP, 0, stream>>>(cntmat, nblkA, part);
    k_bsum2<<<1, NBP, 0, stream>>>(part, bbase);
    k_binB<<<NB, TA, 0, stream>>>(outbuf, cntmat, offmat, bbase, nblkA, N,
                                  csr, meta, x, xs16h, xs17h);

    // layer 1 (persistent): gather + matvec1 + in-block MFMA mm2 -> fp8 hs2
    dim3 blk(256);
    k_gather1<<<gg, blk, 0, stream>>>((const uint4*)xs16h, xs17h, csr, meta,
                                      W1, b1, w2frag, hs2, N, ntiles);

    // layer 2 gather + pool (persistent, fp8 rows L2-resident)
    k_gather2<<<gg, blk, 0, stream>>>((const uint4*)hs2, csr, meta,
                                      b2, batch, pool, cntg, N, ntiles);

    // readout
    k_final<<<G, OUTC, 0, stream>>>(pool, cntg, Wf1, bf1, Wf2, bf2, (float*)d_out, G);
}

// Round 19
// 120.674 us; speedup vs baseline: 1.2926x; 1.1610x over previous
//
#include <hip/hip_runtime.h>

#define IN_C 17
#define HID  64
#define OUTC 32

#define CH   8192      // edges per pass-A block
#define TA   512       // pass-A threads
#define NBP  512       // padded bucket count (bucket = dst>>8; N<=131072)
#define BCAP 5632      // pass-B stage capacity
#define BS_BLKS 8

typedef __attribute__((ext_vector_type(2))) float f2;
typedef __attribute__((ext_vector_type(8))) short bf16x8;
typedef __attribute__((ext_vector_type(4))) float f32x4;
__device__ __forceinline__ f2 mkf2(float x, float y) { f2 r; r.x = x; r.y = y; return r; }

__device__ __forceinline__ unsigned short f2bf(float f) {
    unsigned u = __float_as_uint(f);
    u += 0x7fffu + ((u >> 16) & 1u);      // round-nearest-even
    return (unsigned short)(u >> 16);
}
__device__ __forceinline__ float bflo(unsigned u) { return __uint_as_float(u << 16); }
__device__ __forceinline__ float bfhi(unsigned u) { return __uint_as_float(u & 0xffff0000u); }

// ===== pass A: bin edges by dst>>8 + pool zero + (block 0) W2 fragment pack =====
__global__ __launch_bounds__(TA) void k_binA(const int* __restrict__ src,
        const int* __restrict__ dst, int E,
        int* __restrict__ outbuf, int* __restrict__ cntmat, int* __restrict__ offmat,
        const float* __restrict__ W2, uint4* __restrict__ w2frag,
        float* __restrict__ pool, int poolN) {
    __shared__ int cnt[NBP];
    __shared__ int off[NBP];
    __shared__ int stage[CH];
    int t = threadIdx.x;
    // zero pool+cntg (replaces pathological hipMemsetAsync fill)
    for (int i = (int)(blockIdx.x * TA + t); i < poolN; i += (int)(gridDim.x * TA))
        pool[i] = 0.f;
    // pack W2 into MFMA B-fragment layout (block 0): frag f = kt*2+nt; lane l holds
    // B[k = kt*32 + (l>>4)*8 + j][c = nt*16 + (l&15)], j=0..7
    if (blockIdx.x == 0 && t < 256) {
        int f = t >> 6, l = t & 63;
        int kt = f >> 1, nt = f & 1;
        int kbase = kt * 32 + (l >> 4) * 8;
        int c = nt * 16 + (l & 15);
        unsigned short v[8];
#pragma unroll
        for (int j = 0; j < 8; ++j) v[j] = f2bf(W2[(kbase + j) * OUTC + c]);
        uint4 o;
        o.x = (unsigned)v[0] | ((unsigned)v[1] << 16);
        o.y = (unsigned)v[2] | ((unsigned)v[3] << 16);
        o.z = (unsigned)v[4] | ((unsigned)v[5] << 16);
        o.w = (unsigned)v[6] | ((unsigned)v[7] << 16);
        w2frag[f * 64 + l] = o;
    }
    long base = (long)blockIdx.x * CH;
    int nE = (int)(E - base); if (nE > CH) nE = CH;
    cnt[t] = 0;
    __syncthreads();
    int bk[16], pk[16], rk[16];
#pragma unroll
    for (int j = 0; j < 16; ++j) {
        int idx = t + j * TA;
        if (idx < nE) {
            long e = base + idx;
            int d = __builtin_nontemporal_load(&dst[e]);
            int s = __builtin_nontemporal_load(&src[e]);
            int b = d >> 8;
            bk[j] = b;
            pk[j] = s | ((d & 255) << 17);
            rk[j] = atomicAdd(&cnt[b], 1);
        } else bk[j] = -1;
    }
    __syncthreads();
    int c = cnt[t];
    off[t] = c;
    __syncthreads();
    int inc = c;
    for (int s = 1; s < NBP; s <<= 1) {
        int add = (t >= s) ? off[t - s] : 0;
        __syncthreads();
        inc += add; off[t] = inc;
        __syncthreads();
    }
    int excl = inc - c;
    __syncthreads();
    off[t] = excl;
    __syncthreads();
#pragma unroll
    for (int j = 0; j < 16; ++j)
        if (bk[j] >= 0) stage[off[bk[j]] + rk[j]] = pk[j];
    __syncthreads();
    for (int i = t; i < nE; i += TA) outbuf[base + i] = stage[i];
    cntmat[blockIdx.x * NBP + t] = c;
    offmat[blockIdx.x * NBP + t] = excl;
}

// ============ bucket totals (parallel partial) + exclusive scan ============
__global__ __launch_bounds__(NBP) void k_bsum1(const int* __restrict__ cntmat,
        int nblkA, int* __restrict__ part) {
    int t = threadIdx.x, b = blockIdx.x;
    int per = (nblkA + BS_BLKS - 1) / BS_BLKS;
    int i0 = b * per, i1 = min(i0 + per, nblkA);
    int s = 0;
    for (int i = i0; i < i1; ++i) s += cntmat[i * NBP + t];
    part[b * NBP + t] = s;
}

__global__ __launch_bounds__(NBP) void k_bsum2(const int* __restrict__ part,
        int* __restrict__ bbase) {
    __shared__ int sh[NBP];
    int t = threadIdx.x;
    int s = 0;
#pragma unroll
    for (int i = 0; i < BS_BLKS; ++i) s += part[i * NBP + t];
    sh[t] = s;
    __syncthreads();
    int inc = s;
    for (int st = 1; st < NBP; st <<= 1) {
        int add = (t >= st) ? sh[t - st] : 0;
        __syncthreads();
        inc += add; sh[t] = inc;
        __syncthreads();
    }
    bbase[t] = inc - s;
}

// === pass B: per bucket, gather runs, emit CSR + meta(start,deg) + bf16 xs (fused prep) ===
__global__ __launch_bounds__(TA) void k_binB(const int* __restrict__ outbuf,
        const int* __restrict__ cntmat, const int* __restrict__ offmat,
        const int* __restrict__ bbase, int nblkA, int N,
        int* __restrict__ csr, int2* __restrict__ meta,
        const float* __restrict__ x, unsigned* __restrict__ xs16h,
        unsigned short* __restrict__ xs17h) {
    __shared__ int segc[256], sego[256], segs[256];
    __shared__ int ndeg[256], noff[256];
    __shared__ int stage[BCAP];
    int t = threadIdx.x, b = blockIdx.x;
    if (t < 256) {
        int cc = 0, ss = 0;
        if (t < nblkA) { cc = cntmat[t * NBP + b]; ss = offmat[t * NBP + b]; }
        segc[t] = cc; segs[t] = ss; sego[t] = cc;
        ndeg[t] = 0;
    }
    __syncthreads();
    {
        int c = (t < 256) ? sego[t] : 0;
        int inc = c;
        for (int s = 1; s < 256; s <<= 1) {
            int add = (t < 256 && t >= s) ? sego[t - s] : 0;
            __syncthreads();
            if (t < 256) { inc += add; sego[t] = inc; }
            __syncthreads();
        }
        if (t < 256) sego[t] = inc - c;
    }
    __syncthreads();
    int wave = t >> 6, lane = t & 63;
    for (int i = wave; i < nblkA; i += TA / 64) {
        int c = segc[i], so = sego[i];
        long gs = (long)i * CH + segs[i];
        for (int l = lane; l < c; l += 64) {
            int p = so + l;
            if (p < BCAP) stage[p] = __builtin_nontemporal_load(&outbuf[gs + l]);
        }
    }
    __syncthreads();
    int T = sego[255] + segc[255];
    if (T > BCAP) T = BCAP;
    int mypk[11], myrk[11], ne = 0;
    for (int k = t; k < T; k += TA) {
        int p = stage[k];
        int l = (p >> 17) & 255;
        myrk[ne] = atomicAdd(&ndeg[l], 1);
        mypk[ne] = p;
        ne++;
    }
    __syncthreads();
    {
        int c = (t < 256) ? ndeg[t] : 0;
        if (t < 256) noff[t] = c;
        __syncthreads();
        int inc = c;
        for (int s = 1; s < 256; s <<= 1) {
            int add = (t < 256 && t >= s) ? noff[t - s] : 0;
            __syncthreads();
            if (t < 256) { inc += add; noff[t] = inc; }
            __syncthreads();
        }
        if (t < 256) noff[t] = inc - c;
    }
    __syncthreads();
    int gb = bbase[b];
    int n0 = b << 8;
    if (t < 256 && n0 + t < N) {
        int n = n0 + t;
        meta[n] = make_int2(gb + noff[t], ndeg[t]);
        float dinv = rsqrtf((float)(ndeg[t] + 1));
        const float* xr = x + (size_t)n * IN_C;
        unsigned* xo = xs16h + (size_t)n * 8;
#pragma unroll
        for (int w2 = 0; w2 < 8; ++w2) {
            unsigned lo = f2bf(xr[2 * w2] * dinv);
            unsigned hi = f2bf(xr[2 * w2 + 1] * dinv);
            xo[w2] = lo | (hi << 16);
        }
        xs17h[n] = f2bf(xr[16] * dinv);
    }
    for (int j = 0; j < ne; ++j) {
        int p = mypk[j];
        int l = (p >> 17) & 255;
        csr[gb + noff[l] + myrk[j]] = p & 0x1FFFF;
    }
}

// ---------- layer 1: direct-csr gather -> fold -> matvec1 -> in-block MFMA mm2 -> fp8 hs2 ----------
__global__ __launch_bounds__(256) void k_gather1(
        const uint4* __restrict__ xs16v, const unsigned short* __restrict__ xs17h,
        const int* __restrict__ csr, const int2* __restrict__ meta,
        const float* __restrict__ W1, const float* __restrict__ b1,
        const uint4* __restrict__ w2frag, unsigned char* __restrict__ hs2b, int N) {
    __shared__ __align__(16) float aggx[16][20];
    __shared__ float dinv_sh[16];
    __shared__ __align__(16) float h1sh[16][68];   // holds dinv*relu(h1), f32

    int tid = threadIdx.x;
    int n0 = blockIdx.x * 16;
    int ch = tid & 63;
    float w1r[IN_C];
#pragma unroll
    for (int k = 0; k < IN_C; ++k) w1r[k] = W1[k * HID + ch];
    float b1v = b1[ch];

    int ln = tid >> 4, sl = tid & 15;
    int n = n0 + ln;
    f2 acc[8];
#pragma unroll
    for (int j = 0; j < 8; ++j) acc[j] = mkf2(0.f, 0.f);
    float a17 = 0.f;
    if (n < N) {
        int2 m = meta[n];
        int start = m.x, cnt = m.y, end = start + cnt;
        auto body = [&](int s) {
            uint4 v0 = xs16v[(size_t)s * 2];
            uint4 v1 = xs16v[(size_t)s * 2 + 1];
            acc[0] += mkf2(bflo(v0.x), bfhi(v0.x));
            acc[1] += mkf2(bflo(v0.y), bfhi(v0.y));
            acc[2] += mkf2(bflo(v0.z), bfhi(v0.z));
            acc[3] += mkf2(bflo(v0.w), bfhi(v0.w));
            acc[4] += mkf2(bflo(v1.x), bfhi(v1.x));
            acc[5] += mkf2(bflo(v1.y), bfhi(v1.y));
            acc[6] += mkf2(bflo(v1.z), bfhi(v1.z));
            acc[7] += mkf2(bflo(v1.w), bfhi(v1.w));
            a17 += bflo((unsigned)xs17h[s]);
        };
        for (int k = start + sl; k < end; k += 16)
            body(__builtin_nontemporal_load(&csr[k]));
        if (sl == 0) {                                   // self loop
            body(n);
            dinv_sh[ln] = rsqrtf((float)(cnt + 1));
        }
    }
    float a[16];
#pragma unroll
    for (int j = 0; j < 8; ++j) { a[2 * j] = acc[j].x; a[2 * j + 1] = acc[j].y; }
#pragma unroll
    for (int j = 0; j < 8; ++j) {
        float tt = (sl & 8) ? a[j + 8] : a[j];
        float uu = (sl & 8) ? a[j] : a[j + 8];
        a[j] = tt + __shfl_xor(uu, 8);
    }
#pragma unroll
    for (int j = 0; j < 4; ++j) {
        float tt = (sl & 4) ? a[j + 4] : a[j];
        float uu = (sl & 4) ? a[j] : a[j + 4];
        a[j] = tt + __shfl_xor(uu, 4);
    }
#pragma unroll
    for (int j = 0; j < 2; ++j) {
        float tt = (sl & 2) ? a[j + 2] : a[j];
        float uu = (sl & 2) ? a[j] : a[j + 2];
        a[j] = tt + __shfl_xor(uu, 2);
    }
    {
        float tt = (sl & 1) ? a[1] : a[0];
        float uu = (sl & 1) ? a[0] : a[1];
        a[0] = tt + __shfl_xor(uu, 1);
    }
    a17 += __shfl_xor(a17, 1);
    a17 += __shfl_xor(a17, 2);
    a17 += __shfl_xor(a17, 4);
    a17 += __shfl_xor(a17, 8);
    aggx[ln][sl] = a[0];
    if (sl == 0) aggx[ln][16] = a17;
    __syncthreads();
    // matvec1 + bias + relu; h1sh = dinv * relu(...)  (f32)
    int s0 = tid >> 6;
#pragma unroll
    for (int rep = 0; rep < 4; ++rep) {
        int slot = s0 + rep * 4;
        int nn = n0 + slot;
        if (nn < N) {
            const float4* ap = (const float4*)aggx[slot];
            float4 A0 = ap[0], A1 = ap[1], A2 = ap[2], A3 = ap[3];
            float a16 = aggx[slot][16];
            float dot = A0.x * w1r[0]  + A0.y * w1r[1]  + A0.z * w1r[2]  + A0.w * w1r[3]
                      + A1.x * w1r[4]  + A1.y * w1r[5]  + A1.z * w1r[6]  + A1.w * w1r[7]
                      + A2.x * w1r[8]  + A2.y * w1r[9]  + A2.z * w1r[10] + A2.w * w1r[11]
                      + A3.x * w1r[12] + A3.y * w1r[13] + A3.z * w1r[14] + A3.w * w1r[15]
                      + a16  * w1r[16];
            float dv = dinv_sh[slot];
            h1sh[slot][ch] = dv * fmaxf(dv * dot + b1v, 0.f);
        }
    }
    __syncthreads();
    // mm2 via MFMA on this block's 16 nodes: wave wv computes N-tile wv (cols wv*16..+15)
    int wv = tid >> 6, l = tid & 63;
    if (wv < 2) {
        int row = l & 15, kq = l >> 4;
        const float4* hp = (const float4*)&h1sh[row][kq * 8];
        float4 f0v = hp[0], f1v = hp[1];
        const float4* hq = (const float4*)&h1sh[row][32 + kq * 8];
        float4 g0v = hq[0], g1v = hq[1];
        bf16x8 a0, a1;
        a0[0] = (short)f2bf(f0v.x); a0[1] = (short)f2bf(f0v.y);
        a0[2] = (short)f2bf(f0v.z); a0[3] = (short)f2bf(f0v.w);
        a0[4] = (short)f2bf(f1v.x); a0[5] = (short)f2bf(f1v.y);
        a0[6] = (short)f2bf(f1v.z); a0[7] = (short)f2bf(f1v.w);
        a1[0] = (short)f2bf(g0v.x); a1[1] = (short)f2bf(g0v.y);
        a1[2] = (short)f2bf(g0v.z); a1[3] = (short)f2bf(g0v.w);
        a1[4] = (short)f2bf(g1v.x); a1[5] = (short)f2bf(g1v.y);
        a1[6] = (short)f2bf(g1v.z); a1[7] = (short)f2bf(g1v.w);
        bf16x8 bA = *(const bf16x8*)&w2frag[(0 + wv) * 64 + l];   // kt0, nt=wv
        bf16x8 bB = *(const bf16x8*)&w2frag[(2 + wv) * 64 + l];   // kt1, nt=wv
        f32x4 d = {0.f, 0.f, 0.f, 0.f};
        d = __builtin_amdgcn_mfma_f32_16x16x32_bf16(a0, bA, d, 0, 0, 0);
        d = __builtin_amdgcn_mfma_f32_16x16x32_bf16(a1, bB, d, 0, 0, 0);
        int rbase = (l >> 4) * 4;
#pragma unroll
        for (int r = 0; r < 4; ++r) {
            int node = n0 + rbase + r;
            if (node < N) {
                unsigned pk = (unsigned)__builtin_amdgcn_cvt_pk_fp8_f32(d[r], 0.f, 0, false);
                hs2b[(size_t)node * 32 + wv * 16 + (l & 15)] = (unsigned char)(pk & 0xFFu);
            }
        }
    }
}

// ---------- layer 2 gather: direct-csr, 1 lane/edge, fp8 rows (HW cvt) + pool ----------
__global__ __launch_bounds__(256) void k_gather2(
        const uint4* __restrict__ hs2v, const int* __restrict__ csr,
        const int2* __restrict__ meta, const float* __restrict__ b2,
        const int* __restrict__ batch, float* pool, float* cntg, int N) {
    __shared__ __align__(16) float cont[16][OUTC];
    __shared__ int bsh[16];
    int tid = threadIdx.x;
    int n0 = blockIdx.x * 16;

    int ln = tid >> 4, sl = tid & 15;
    int n = n0 + ln;
    f2 acc[16];
#pragma unroll
    for (int j = 0; j < 16; ++j) acc[j] = mkf2(0.f, 0.f);
    float dinv = 0.f;
    if (n < N) {
        int2 m = meta[n];
        int start = m.x, cnt = m.y, end = start + cnt;
        dinv = rsqrtf((float)(cnt + 1));
        auto body = [&](int s) {
            const uint4* rp = hs2v + (size_t)s * 2;
            uint4 v0 = rp[0], v1 = rp[1];
            f2 t;
            t = __builtin_amdgcn_cvt_pk_f32_fp8((int)v0.x, false); acc[0]  += t;
            t = __builtin_amdgcn_cvt_pk_f32_fp8((int)v0.x, true);  acc[1]  += t;
            t = __builtin_amdgcn_cvt_pk_f32_fp8((int)v0.y, false); acc[2]  += t;
            t = __builtin_amdgcn_cvt_pk_f32_fp8((int)v0.y, true);  acc[3]  += t;
            t = __builtin_amdgcn_cvt_pk_f32_fp8((int)v0.z, false); acc[4]  += t;
            t = __builtin_amdgcn_cvt_pk_f32_fp8((int)v0.z, true);  acc[5]  += t;
            t = __builtin_amdgcn_cvt_pk_f32_fp8((int)v0.w, false); acc[6]  += t;
            t = __builtin_amdgcn_cvt_pk_f32_fp8((int)v0.w, true);  acc[7]  += t;
            t = __builtin_amdgcn_cvt_pk_f32_fp8((int)v1.x, false); acc[8]  += t;
            t = __builtin_amdgcn_cvt_pk_f32_fp8((int)v1.x, true);  acc[9]  += t;
            t = __builtin_amdgcn_cvt_pk_f32_fp8((int)v1.y, false); acc[10] += t;
            t = __builtin_amdgcn_cvt_pk_f32_fp8((int)v1.y, true);  acc[11] += t;
            t = __builtin_amdgcn_cvt_pk_f32_fp8((int)v1.z, false); acc[12] += t;
            t = __builtin_amdgcn_cvt_pk_f32_fp8((int)v1.z, true);  acc[13] += t;
            t = __builtin_amdgcn_cvt_pk_f32_fp8((int)v1.w, false); acc[14] += t;
            t = __builtin_amdgcn_cvt_pk_f32_fp8((int)v1.w, true);  acc[15] += t;
        };
        for (int k = start + sl; k < end; k += 16)
            body(__builtin_nontemporal_load(&csr[k]));
        if (sl == 0) body(n);                            // self loop
    }
    float a[32];
#pragma unroll
    for (int j = 0; j < 16; ++j) { a[2 * j] = acc[j].x; a[2 * j + 1] = acc[j].y; }
    // halving fold: lane sl ends with channels (2sl, 2sl+1) in a[0], a[1]
#pragma unroll
    for (int j = 0; j < 16; ++j) {
        float tt = (sl & 8) ? a[j + 16] : a[j];
        float uu = (sl & 8) ? a[j] : a[j + 16];
        a[j] = tt + __shfl_xor(uu, 8);
    }
#pragma unroll
    for (int j = 0; j < 8; ++j) {
        float tt = (sl & 4) ? a[j + 8] : a[j];
        float uu = (sl & 4) ? a[j] : a[j + 8];
        a[j] = tt + __shfl_xor(uu, 4);
    }
#pragma unroll
    for (int j = 0; j < 4; ++j) {
        float tt = (sl & 2) ? a[j + 4] : a[j];
        float uu = (sl & 2) ? a[j] : a[j + 4];
        a[j] = tt + __shfl_xor(uu, 2);
    }
#pragma unroll
    for (int j = 0; j < 2; ++j) {
        float tt = (sl & 1) ? a[j + 2] : a[j];
        float uu = (sl & 1) ? a[j] : a[j + 2];
        a[j] = tt + __shfl_xor(uu, 1);
    }
    if (n < N) {
        float c0 = dinv * a[0] + b2[2 * sl];
        float c1 = dinv * a[1] + b2[2 * sl + 1];
        *(float2*)&cont[ln][2 * sl] = make_float2(c0, c1);
        if (sl == 0) bsh[ln] = batch[n];
    } else {
        *(float2*)&cont[ln][2 * sl] = make_float2(0.f, 0.f);
        if (sl == 0) bsh[ln] = -1;
    }
    __syncthreads();
    if (tid < OUTC) {
        int c = tid;
        float run = 0.f; int cur = -1;
        for (int j = 0; j < 16; ++j) {
            int bj = bsh[j];
            if (bj < 0) continue;
            if (bj == cur) run += cont[j][c];
            else {
                if (cur >= 0) atomicAdd(&pool[(size_t)cur * OUTC + c], run);
                cur = bj; run = cont[j][c];
            }
        }
        if (cur >= 0) atomicAdd(&pool[(size_t)cur * OUTC + c], run);
        if (c == 0) {
            float crun = 0.f; cur = -1;
            for (int j = 0; j < 16; ++j) {
                int bj = bsh[j];
                if (bj < 0) continue;
                if (bj == cur) crun += 1.f;
                else {
                    if (cur >= 0) atomicAdd(&cntg[cur], crun);
                    cur = bj; crun = 1.f;
                }
            }
            if (cur >= 0) atomicAdd(&cntg[cur], crun);
        }
    }
}

// ---------- final: pooled mean -> fc1(relu) -> fc2 ----------
__global__ void k_final(const float* __restrict__ pool, const float* __restrict__ cntg,
                        const float* __restrict__ Wf1, const float* __restrict__ bf1,
                        const float* __restrict__ Wf2, const float* __restrict__ bf2,
                        float* out, int G) {
    __shared__ float p[OUTC], t[OUTC];
    int g = blockIdx.x;
    int c = threadIdx.x;
    float csafe = fmaxf(cntg[g], 1.0f);
    p[c] = pool[g * OUTC + c] / csafe;
    __syncthreads();
    float acc = bf1[c];
#pragma unroll
    for (int k = 0; k < OUTC; ++k) acc += p[k] * Wf1[k * OUTC + c];
    t[c] = fmaxf(acc, 0.f);
    __syncthreads();
    float acc2 = bf2[c];
#pragma unroll
    for (int k = 0; k < OUTC; ++k) acc2 += t[k] * Wf2[k * OUTC + c];
    out[g * OUTC + c] = acc2;
}

extern "C" void kernel_launch(void* const* d_in, const int* in_sizes, int n_in,
                              void* d_out, int out_size, void* d_ws, size_t ws_size,
                              hipStream_t stream) {
    const float* x    = (const float*)d_in[0];
    const int*   ei   = (const int*)  d_in[1];
    const int*   batch= (const int*)  d_in[2];
    const float* W1   = (const float*)d_in[3];
    const float* b1   = (const float*)d_in[4];
    const float* W2   = (const float*)d_in[5];
    const float* b2   = (const float*)d_in[6];
    const float* Wf1  = (const float*)d_in[7];
    const float* bf1  = (const float*)d_in[8];
    const float* Wf2  = (const float*)d_in[9];
    const float* bf2  = (const float*)d_in[10];

    const int N = in_sizes[0] / IN_C;
    const int E = in_sizes[1] / 2;
    const int G = out_size / OUTC;
    const int* src = ei;
    const int* dst = ei + E;

    const int nblkA = (E + CH - 1) / CH;
    const int NB    = (N + 255) >> 8;

    // ---- workspace layout ----
    char* w = (char*)d_ws;
    int*   csr      = (int*)w;   w += (size_t)E * sizeof(int);
    int2*  meta     = (int2*)w;  w += (size_t)N * sizeof(int2);
    unsigned* xs16h = (unsigned*)w; w += (size_t)N * 8 * sizeof(unsigned);
    unsigned char* hs2 = (unsigned char*)w; w += (size_t)N * 32;   // fp8 rows, 32B
    unsigned short* xs17h = (unsigned short*)w; w += (size_t)N * sizeof(unsigned short);
    w = (char*)(((size_t)w + 15) & ~(size_t)15);
    float* pool     = (float*)w; w += (size_t)G * OUTC * sizeof(float);
    float* cntg     = (float*)w; w += (size_t)G * sizeof(float);
    w = (char*)(((size_t)w + 15) & ~(size_t)15);
    int*   outbuf   = (int*)w;   w += (size_t)E * sizeof(int);
    int*   cntmat   = (int*)w;   w += (size_t)nblkA * NBP * sizeof(int);
    int*   offmat   = (int*)w;   w += (size_t)nblkA * NBP * sizeof(int);
    int*   bbase    = (int*)w;   w += NBP * sizeof(int);
    int*   part     = (int*)w;   w += BS_BLKS * NBP * sizeof(int);
    w = (char*)(((size_t)w + 15) & ~(size_t)15);
    uint4* w2frag   = (uint4*)w; w += 4 * 64 * sizeof(uint4);

    const int poolN = G * OUTC + G;   // pool + cntg are contiguous floats

    // CSR build (counting sort) + fused x prep + W2 fragment pack + pool zero
    k_binA<<<nblkA, TA, 0, stream>>>(src, dst, E, outbuf, cntmat, offmat,
                                     W2, w2frag, pool, poolN);
    k_bsum1<<<BS_BLKS, NBP, 0, stream>>>(cntmat, nblkA, part);
    k_bsum2<<<1, NBP, 0, stream>>>(part, bbase);
    k_binB<<<NB, TA, 0, stream>>>(outbuf, cntmat, offmat, bbase, nblkA, N,
                                  csr, meta, x, xs16h, xs17h);

    // layer 1: gather + matvec1 + in-block MFMA mm2 -> fp8 hs2 (natural ch order)
    dim3 blk(256);
    k_gather1<<<(N + 15) / 16, blk, 0, stream>>>((const uint4*)xs16h, xs17h, csr, meta,
                                                 W1, b1, w2frag, hs2, N);

    // layer 2 gather + pool (fp8 rows, L2-resident)
    k_gather2<<<(N + 15) / 16, blk, 0, stream>>>((const uint4*)hs2, csr, meta,
                                                 b2, batch, pool, cntg, N);

    // readout
    k_final<<<G, OUTC, 0, stream>>>(pool, cntg, Wf1, bf1, Wf2, bf2, (float*)d_out, G);
}